// Round 15
// baseline (152.209 us; speedup 1.0000x reference)
//
#include <hip/hip_runtime.h>
#include <hip/hip_bf16.h>

typedef __attribute__((ext_vector_type(8))) short short8;
typedef __attribute__((ext_vector_type(4))) float f32x4;

#define MTOT 8192      // B*P
#define DDIM 256
#define BM   128       // rows per block (4 waves x 32 rows each)
#define BN   32        // keys per LDS tile (2 col-tiles of 16) = 16KB
#define SPLITS 32
#define KPS (MTOT / SPLITS)          // 256 keys per split
#define NIT (KPS / BN)               // 8 iters
#define NFRAG (MTOT * 32)            // 262144 short8 fragments per tensor

static constexpr float INV_T_F = 14.285714285714286f;   // 1/0.07
static constexpr float LOG2E   = 1.4426950408889634f;
static constexpr float LN2     = 0.6931471805599453f;
static constexpr float ALPHA   = INV_T_F * LOG2E;       // folded into q fragments

__device__ __forceinline__ unsigned short f2bf(float f) {
    union { float f; unsigned int u; } v; v.f = f;
    unsigned int r = v.u + 0x7fffu + ((v.u >> 16) & 1u);  // round-nearest-even
    return (unsigned short)(r >> 16);
}
// raw v_exp_f32: args are always <= 0 here; -huge flushes to 0 (correct)
#define EXP2R(x) __builtin_amdgcn_exp2f(x)

// Fragment layout (both tensors): frag[(tile*8 + kk)*64 + lane] holds
// x[tile*16 + (lane&15)][kk*32 + (lane>>4)*8 .. +8] as bf16 short8 (q scaled
// by ALPHA). Coalesced fp32 reads; scattered 16B writes (posted, L2 absorbs).
// 32 threads of a row also produce the EXACT fp32 positive dot -> dots[].
__global__ void convert_kernel(const float* __restrict__ q, const float* __restrict__ k,
                               short8* __restrict__ qbT, short8* __restrict__ kbT,
                               float* __restrict__ dots) {
    const int g   = blockIdx.x * blockDim.x + threadIdx.x;   // 0 .. NFRAG-1
    const int row = g >> 5;        // source row
    const int c8  = g & 31;        // 8-dim chunk within row
    const float4* q4 = (const float4*)q;
    const float4* k4 = (const float4*)k;
    const float4 qa = q4[(size_t)g * 2], qb = q4[(size_t)g * 2 + 1];
    const float4 ka = k4[(size_t)g * 2], kb = k4[(size_t)g * 2 + 1];

    short8 oq, ok;
    oq[0] = (short)f2bf(qa.x * ALPHA); oq[1] = (short)f2bf(qa.y * ALPHA);
    oq[2] = (short)f2bf(qa.z * ALPHA); oq[3] = (short)f2bf(qa.w * ALPHA);
    oq[4] = (short)f2bf(qb.x * ALPHA); oq[5] = (short)f2bf(qb.y * ALPHA);
    oq[6] = (short)f2bf(qb.z * ALPHA); oq[7] = (short)f2bf(qb.w * ALPHA);
    ok[0] = (short)f2bf(ka.x); ok[1] = (short)f2bf(ka.y);
    ok[2] = (short)f2bf(ka.z); ok[3] = (short)f2bf(ka.w);
    ok[4] = (short)f2bf(kb.x); ok[5] = (short)f2bf(kb.y);
    ok[6] = (short)f2bf(kb.z); ok[7] = (short)f2bf(kb.w);
    const int dst = ((row >> 4) * 8 + (c8 >> 2)) * 64 + (c8 & 3) * 16 + (row & 15);
    qbT[dst] = oq;
    kbT[dst] = ok;

    float d = qa.x * ka.x + qa.y * ka.y + qa.z * ka.z + qa.w * ka.w
            + qb.x * kb.x + qb.y * kb.y + qb.z * kb.z + qb.w * kb.w;
#pragma unroll
    for (int s = 1; s < 32; s <<= 1) d += __shfl_xor(d, s);
    if (c8 == 0) dots[row] = d;
}

// One wave stages a contiguous 4KB chunk (256 short8) via 4 global_load_lds
// width=16. LDS dest is wave-uniform base + lane*16 (HW rule).
__device__ __forceinline__ void stage_chunk(const short8* __restrict__ src_base,
                                            short8* lds_base, int lane) {
#pragma unroll
    for (int i = 0; i < 4; ++i) {
        const short8* g = src_base + i * 64 + lane;
        short8* l = lds_base + i * 64;
        __builtin_amdgcn_global_load_lds(
            (const __attribute__((address_space(1))) unsigned int*)g,
            (__attribute__((address_space(3))) unsigned int*)l,
            16, 0, 0);
    }
}

// Flash-LSE partials: grid (64, 32) = 2048 blocks, 3 resident/CU
// (LDS 3x32KB = 96KB) -> 2.67 batches (small tail).
// K tile (32 keys = 16KB) double-buffered; fragments lane-linear ->
// conflict-free ds_read_b128. Q fragments (qf[2][8] = 64 VGPR) in registers.
// Plain online LSE (r12 form): the defer-max/setprio variants measured WORSE
// (r14: VALUBusy 36->56%, flash 44->48us) -- do not re-add.
// C/D map: col=lane&15, row=(lane>>4)*4+reg [verified r2..r14 pass].
__global__ __launch_bounds__(256, 3) void flash_lse_kernel(
        const short8* __restrict__ qbT,
        const short8* __restrict__ kbT,
        float* __restrict__ part_m,
        float* __restrict__ part_s) {
    __shared__ short8 smem[2][1024];   // 2 x 16KB

    const int mblk  = blockIdx.x;
    const int split = blockIdx.y;
    const int wid   = threadIdx.x >> 6;
    const int lane  = threadIdx.x & 63;
    const int l16   = lane & 15;
    const int lg    = lane >> 4;
    const int rt16  = mblk * 8 + wid * 2;   // first of this wave's two row-tiles

    // Hoist Q fragments: 16 coalesced 1KB loads, live for the whole kernel.
    short8 qf[2][8];
#pragma unroll
    for (int rt = 0; rt < 2; ++rt)
#pragma unroll
        for (int kk = 0; kk < 8; ++kk)
            qf[rt][kk] = qbT[(size_t)((rt16 + rt) * 8 + kk) * 64 + lane];

    float m_loc[2][4], s_loc[2][4];
#pragma unroll
    for (int rt = 0; rt < 2; ++rt)
#pragma unroll
        for (int j = 0; j < 4; ++j) { m_loc[rt][j] = -1e30f; s_loc[rt][j] = 0.f; }

    // split covers 16 col-tiles from split*16; iter covers 2 col-tiles
    // (32 keys = 1024 contiguous short8 = 16KB).
    const size_t tile_base0 = (size_t)split * 8192;

    // prologue: stage tile 0 into buf 0 (each of 4 waves stages 4KB)
    stage_chunk(kbT + tile_base0 + wid * 256, &smem[0][wid * 256], lane);
    __syncthreads();   // drains vmcnt -> tile 0 resident

    for (int it = 0; it < NIT; ++it) {
        const int cur = it & 1;
        if (it + 1 < NIT) {
            const size_t nbase = tile_base0 + (size_t)(it + 1) * 1024;
            stage_chunk(kbT + nbase + wid * 256, &smem[cur ^ 1][wid * 256], lane);
        }

        f32x4 acc[2][2];
#pragma unroll
        for (int rt = 0; rt < 2; ++rt)
#pragma unroll
            for (int ct = 0; ct < 2; ++ct)
                acc[rt][ct] = (f32x4){0.f, 0.f, 0.f, 0.f};

        const short8* sb = smem[cur];
#pragma unroll
        for (int kk = 0; kk < 8; ++kk) {
            short8 bf[2];
#pragma unroll
            for (int ct = 0; ct < 2; ++ct)
                bf[ct] = sb[ct * 512 + kk * 64 + lane];
#pragma unroll
            for (int rt = 0; rt < 2; ++rt)
#pragma unroll
                for (int ct = 0; ct < 2; ++ct)
                    acc[rt][ct] = __builtin_amdgcn_mfma_f32_16x16x32_bf16(
                        qf[rt][kk], bf[ct], acc[rt][ct], 0, 0, 0);
        }

        // plain online LSE update (base-2), per-lane partial over cols
#pragma unroll
        for (int rt = 0; rt < 2; ++rt) {
#pragma unroll
            for (int j = 0; j < 4; ++j) {
                const float x0 = acc[rt][0][j], x1 = acc[rt][1][j];
                const float mo = m_loc[rt][j];
                const float mn = fmaxf(fmaxf(x0, x1), mo);
                float s = s_loc[rt][j] * EXP2R(mo - mn);
                s += EXP2R(x0 - mn) + EXP2R(x1 - mn);
                m_loc[rt][j] = mn;
                s_loc[rt][j] = s;
            }
        }

        __syncthreads();   // next tile landed (vmcnt drain) + all waves done with cur
    }

    // reduce (m,s) across the 16 lanes holding different columns of each row
#pragma unroll
    for (int rt = 0; rt < 2; ++rt) {
#pragma unroll
        for (int j = 0; j < 4; ++j) {
            float m = m_loc[rt][j], s = s_loc[rt][j];
#pragma unroll
            for (int d = 1; d < 16; d <<= 1) {
                const float mo = __shfl_xor(m, d);
                const float so = __shfl_xor(s, d);
                const float mn = fmaxf(m, mo);
                s = s * EXP2R(m - mn) + so * EXP2R(mo - mn);
                m = mn;
            }
            if (l16 == 0) {
                const int row = (rt16 + rt) * 16 + lg * 4 + j;
                part_m[split * MTOT + row] = m;
                part_s[split * MTOT + row] = s;
            }
        }
    }
}

// 32 lanes per row (2 rows/wave): merge the 32 split-partials + dot -> loss.
__global__ void combine_kernel(const float* __restrict__ dots,
                               const float* __restrict__ part_m,
                               const float* __restrict__ part_s,
                               float* __restrict__ out) {
    const int tid  = blockIdx.x * blockDim.x + threadIdx.x;
    const int row  = tid >> 5;
    const int l32  = tid & 31;
    float m = part_m[l32 * MTOT + row];
    float s = part_s[l32 * MTOT + row];
#pragma unroll
    for (int d = 1; d < 32; d <<= 1) {
        const float mo = __shfl_xor(m, d);
        const float so = __shfl_xor(s, d);
        const float mn = fmaxf(m, mo);
        s = s * EXP2R(m - mn) + so * EXP2R(mo - mn);
        m = mn;
    }
    if (l32 == 0) {
        out[row] = (m + __log2f(s)) * LN2 - INV_T_F * dots[row];
    }
}

extern "C" void kernel_launch(void* const* d_in, const int* in_sizes, int n_in,
                              void* d_out, int out_size, void* d_ws, size_t ws_size,
                              hipStream_t stream) {
    const float* q = (const float*)d_in[0];
    const float* k = (const float*)d_in[1];
    float* out = (float*)d_out;

    char* ws = (char*)d_ws;
    short8* qbT   = (short8*)ws;                                    // 4 MB
    short8* kbT   = (short8*)(ws + (size_t)NFRAG * 16);             // 4 MB
    float* part_m = (float*)(ws + (size_t)NFRAG * 32);              // 1 MB
    float* part_s = part_m + SPLITS * MTOT;                         // 1 MB
    float* dots   = part_s + SPLITS * MTOT;                         // 32 KB

    convert_kernel<<<NFRAG / 256, 256, 0, stream>>>(q, k, qbT, kbT, dots);
    dim3 grid(MTOT / BM, SPLITS);
    flash_lse_kernel<<<grid, 256, 0, stream>>>(qbT, kbT, part_m, part_s);
    combine_kernel<<<(MTOT * 32) / 256, 256, 0, stream>>>(dots, part_m, part_s, out);
}

// Round 16
// 106.937 us; speedup vs baseline: 1.4234x; 1.4234x over previous
//
#include <hip/hip_runtime.h>
#include <hip/hip_bf16.h>

typedef __attribute__((ext_vector_type(8))) short short8;
typedef __attribute__((ext_vector_type(4))) float f32x4;

#define MTOT 8192      // B*P
#define DDIM 256
#define BM   128       // rows per block (4 waves x 32 rows each)
#define BN   32        // keys per LDS tile (2 col-tiles of 16) = 16KB
#define SPLITS 32
#define KPS (MTOT / SPLITS)          // 256 keys per split
#define NIT (KPS / BN)               // 8 iters
#define NFRAG (MTOT * 32)            // 262144 short8 fragments per tensor

static constexpr float INV_T_F = 14.285714285714286f;   // 1/0.07
static constexpr float LOG2E   = 1.4426950408889634f;
static constexpr float LN2     = 0.6931471805599453f;
static constexpr float ALPHA   = INV_T_F * LOG2E;       // folded into q fragments

__device__ __forceinline__ unsigned short f2bf(float f) {
    union { float f; unsigned int u; } v; v.f = f;
    unsigned int r = v.u + 0x7fffu + ((v.u >> 16) & 1u);  // round-nearest-even
    return (unsigned short)(r >> 16);
}
// raw v_exp_f32: args are always <= 0 here; -huge flushes to 0 (correct)
#define EXP2R(x) __builtin_amdgcn_exp2f(x)

// Fragment layout (both tensors): frag[(tile*8 + kk)*64 + lane] holds
// x[tile*16 + (lane&15)][kk*32 + (lane>>4)*8 .. +8] as bf16 short8 (q scaled
// by ALPHA). Coalesced fp32 reads; scattered 16B writes (posted, L2 absorbs).
// 32 threads of a row also produce the EXACT fp32 positive dot -> dots[].
__global__ void convert_kernel(const float* __restrict__ q, const float* __restrict__ k,
                               short8* __restrict__ qbT, short8* __restrict__ kbT,
                               float* __restrict__ dots) {
    const int g   = blockIdx.x * blockDim.x + threadIdx.x;   // 0 .. NFRAG-1
    const int row = g >> 5;        // source row
    const int c8  = g & 31;        // 8-dim chunk within row
    const float4* q4 = (const float4*)q;
    const float4* k4 = (const float4*)k;
    const float4 qa = q4[(size_t)g * 2], qb = q4[(size_t)g * 2 + 1];
    const float4 ka = k4[(size_t)g * 2], kb = k4[(size_t)g * 2 + 1];

    short8 oq, ok;
    oq[0] = (short)f2bf(qa.x * ALPHA); oq[1] = (short)f2bf(qa.y * ALPHA);
    oq[2] = (short)f2bf(qa.z * ALPHA); oq[3] = (short)f2bf(qa.w * ALPHA);
    oq[4] = (short)f2bf(qb.x * ALPHA); oq[5] = (short)f2bf(qb.y * ALPHA);
    oq[6] = (short)f2bf(qb.z * ALPHA); oq[7] = (short)f2bf(qb.w * ALPHA);
    ok[0] = (short)f2bf(ka.x); ok[1] = (short)f2bf(ka.y);
    ok[2] = (short)f2bf(ka.z); ok[3] = (short)f2bf(ka.w);
    ok[4] = (short)f2bf(kb.x); ok[5] = (short)f2bf(kb.y);
    ok[6] = (short)f2bf(kb.z); ok[7] = (short)f2bf(kb.w);
    const int dst = ((row >> 4) * 8 + (c8 >> 2)) * 64 + (c8 & 3) * 16 + (row & 15);
    qbT[dst] = oq;
    kbT[dst] = ok;

    float d = qa.x * ka.x + qa.y * ka.y + qa.z * ka.z + qa.w * ka.w
            + qb.x * kb.x + qb.y * kb.y + qb.z * kb.z + qb.w * kb.w;
#pragma unroll
    for (int s = 1; s < 32; s <<= 1) d += __shfl_xor(d, s);
    if (c8 == 0) dots[row] = d;
}

// One wave stages a contiguous 4KB chunk (256 short8) via 4 global_load_lds
// width=16. LDS dest is wave-uniform base + lane*16 (HW rule).
__device__ __forceinline__ void stage_chunk(const short8* __restrict__ src_base,
                                            short8* lds_base, int lane) {
#pragma unroll
    for (int i = 0; i < 4; ++i) {
        const short8* g = src_base + i * 64 + lane;
        short8* l = lds_base + i * 64;
        __builtin_amdgcn_global_load_lds(
            (const __attribute__((address_space(1))) unsigned int*)g,
            (__attribute__((address_space(3))) unsigned int*)l,
            16, 0, 0);
    }
}

// Flash-LSE partials: grid (64, 32) = 2048 blocks, 3 resident/CU
// (LDS 3x32KB = 96KB) -> 2.67 batches (small tail).
// K tile (32 keys = 16KB) double-buffered; fragments lane-linear ->
// conflict-free ds_read_b128. Q fragments (qf[2][8] = 64 VGPR) in registers.
// LESSON (r15): the NIT loop MUST NOT be unrolled -- at NIT=8 the compiler
// fully unrolled it, cross-scheduled 8 iterations, exploded live ranges and
// spilled (FETCH 76MB, WRITE 114MB, flash 88us). #pragma unroll 1 pins it.
// C/D map: col=lane&15, row=(lane>>4)*4+reg [verified r2..r15 pass].
__global__ __launch_bounds__(256, 3) void flash_lse_kernel(
        const short8* __restrict__ qbT,
        const short8* __restrict__ kbT,
        float* __restrict__ part_m,
        float* __restrict__ part_s) {
    __shared__ short8 smem[2][1024];   // 2 x 16KB

    const int mblk  = blockIdx.x;
    const int split = blockIdx.y;
    const int wid   = threadIdx.x >> 6;
    const int lane  = threadIdx.x & 63;
    const int l16   = lane & 15;
    const int lg    = lane >> 4;
    const int rt16  = mblk * 8 + wid * 2;   // first of this wave's two row-tiles

    // Hoist Q fragments: 16 coalesced 1KB loads, live for the whole kernel.
    short8 qf[2][8];
#pragma unroll
    for (int rt = 0; rt < 2; ++rt)
#pragma unroll
        for (int kk = 0; kk < 8; ++kk)
            qf[rt][kk] = qbT[(size_t)((rt16 + rt) * 8 + kk) * 64 + lane];

    float m_loc[2][4], s_loc[2][4];
#pragma unroll
    for (int rt = 0; rt < 2; ++rt)
#pragma unroll
        for (int j = 0; j < 4; ++j) { m_loc[rt][j] = -1e30f; s_loc[rt][j] = 0.f; }

    // split covers 16 col-tiles from split*16; iter covers 2 col-tiles
    // (32 keys = 1024 contiguous short8 = 16KB).
    const size_t tile_base0 = (size_t)split * 8192;

    // prologue: stage tile 0 into buf 0 (each of 4 waves stages 4KB)
    stage_chunk(kbT + tile_base0 + wid * 256, &smem[0][wid * 256], lane);
    __syncthreads();   // drains vmcnt -> tile 0 resident

#pragma unroll 1
    for (int it = 0; it < NIT; ++it) {
        const int cur = it & 1;
        if (it + 1 < NIT) {
            const size_t nbase = tile_base0 + (size_t)(it + 1) * 1024;
            stage_chunk(kbT + nbase + wid * 256, &smem[cur ^ 1][wid * 256], lane);
        }

        f32x4 acc[2][2];
#pragma unroll
        for (int rt = 0; rt < 2; ++rt)
#pragma unroll
            for (int ct = 0; ct < 2; ++ct)
                acc[rt][ct] = (f32x4){0.f, 0.f, 0.f, 0.f};

        const short8* sb = smem[cur];
#pragma unroll
        for (int kk = 0; kk < 8; ++kk) {
            short8 bf[2];
#pragma unroll
            for (int ct = 0; ct < 2; ++ct)
                bf[ct] = sb[ct * 512 + kk * 64 + lane];
#pragma unroll
            for (int rt = 0; rt < 2; ++rt)
#pragma unroll
                for (int ct = 0; ct < 2; ++ct)
                    acc[rt][ct] = __builtin_amdgcn_mfma_f32_16x16x32_bf16(
                        qf[rt][kk], bf[ct], acc[rt][ct], 0, 0, 0);
        }

        // plain online LSE update (base-2), per-lane partial over cols
#pragma unroll
        for (int rt = 0; rt < 2; ++rt) {
#pragma unroll
            for (int j = 0; j < 4; ++j) {
                const float x0 = acc[rt][0][j], x1 = acc[rt][1][j];
                const float mo = m_loc[rt][j];
                const float mn = fmaxf(fmaxf(x0, x1), mo);
                float s = s_loc[rt][j] * EXP2R(mo - mn);
                s += EXP2R(x0 - mn) + EXP2R(x1 - mn);
                m_loc[rt][j] = mn;
                s_loc[rt][j] = s;
            }
        }

        __syncthreads();   // next tile landed (vmcnt drain) + all waves done with cur
    }

    // reduce (m,s) across the 16 lanes holding different columns of each row
#pragma unroll
    for (int rt = 0; rt < 2; ++rt) {
#pragma unroll
        for (int j = 0; j < 4; ++j) {
            float m = m_loc[rt][j], s = s_loc[rt][j];
#pragma unroll
            for (int d = 1; d < 16; d <<= 1) {
                const float mo = __shfl_xor(m, d);
                const float so = __shfl_xor(s, d);
                const float mn = fmaxf(m, mo);
                s = s * EXP2R(m - mn) + so * EXP2R(mo - mn);
                m = mn;
            }
            if (l16 == 0) {
                const int row = (rt16 + rt) * 16 + lg * 4 + j;
                part_m[split * MTOT + row] = m;
                part_s[split * MTOT + row] = s;
            }
        }
    }
}

// 32 lanes per row (2 rows/wave): merge the 32 split-partials + dot -> loss.
__global__ void combine_kernel(const float* __restrict__ dots,
                               const float* __restrict__ part_m,
                               const float* __restrict__ part_s,
                               float* __restrict__ out) {
    const int tid  = blockIdx.x * blockDim.x + threadIdx.x;
    const int row  = tid >> 5;
    const int l32  = tid & 31;
    float m = part_m[l32 * MTOT + row];
    float s = part_s[l32 * MTOT + row];
#pragma unroll
    for (int d = 1; d < 32; d <<= 1) {
        const float mo = __shfl_xor(m, d);
        const float so = __shfl_xor(s, d);
        const float mn = fmaxf(m, mo);
        s = s * EXP2R(m - mn) + so * EXP2R(mo - mn);
        m = mn;
    }
    if (l32 == 0) {
        out[row] = (m + __log2f(s)) * LN2 - INV_T_F * dots[row];
    }
}

extern "C" void kernel_launch(void* const* d_in, const int* in_sizes, int n_in,
                              void* d_out, int out_size, void* d_ws, size_t ws_size,
                              hipStream_t stream) {
    const float* q = (const float*)d_in[0];
    const float* k = (const float*)d_in[1];
    float* out = (float*)d_out;

    char* ws = (char*)d_ws;
    short8* qbT   = (short8*)ws;                                    // 4 MB
    short8* kbT   = (short8*)(ws + (size_t)NFRAG * 16);             // 4 MB
    float* part_m = (float*)(ws + (size_t)NFRAG * 32);              // 1 MB
    float* part_s = part_m + SPLITS * MTOT;                         // 1 MB
    float* dots   = part_s + SPLITS * MTOT;                         // 32 KB

    convert_kernel<<<NFRAG / 256, 256, 0, stream>>>(q, k, qbT, kbT, dots);
    dim3 grid(MTOT / BM, SPLITS);
    flash_lse_kernel<<<grid, 256, 0, stream>>>(qbT, kbT, part_m, part_s);
    combine_kernel<<<(MTOT * 32) / 256, 256, 0, stream>>>(dots, part_m, part_s, out);
}